// Round 16
// baseline (238.937 us; speedup 1.0000x reference)
//
#include <hip/hip_runtime.h>

// Depthwise separable 4x4 FIR blur (StyleGAN2 upfirdn2d, up=down=1, pad=(2,2)).
// x: [B,C,256,256] f32, kernel: [4,4] f32 separable, out: [B,C,257,257] f32.
//
// out[q] = H[q+1] + v1*H[q] + v2*H[q-1] + v3*H[q-2],  H[r][c] = sum_j w[j]*x[r][c+1-j]
//
// R16 = R12 (best, 210.6us) + ALIGNED STORE RE-SLICING.
// OW=257 -> row q of plane p starts at dword offset 66049p+257q, i.e.
// (p+q) mod 4 dwords off 16B alignment. R12's dwordx4 stores are then
// 4B-aligned: 1 in 4 lanes straddles a 64B line (+19% write-path line
// transactions) — the last identified mechanism for the 210us plateau
// (81% of float4-copy rate; amp lever exhausted by R15's null).
// Fix: per row, store the 16B-ALIGNED window [4-s .. 4-s+252): lane i
// builds its aligned float4 from own res + next lane's low elems (3
// bpermutes, wave-uniform s); head 4-s dwords by lane 0, tail 1+s dwords
// (incl col 256) by lane 63. Everything else identical to R12.

#define IW 256
#define IH 256
#define OW 257
#define OH 257
#define HSTR 260          // LDS H-row stride in floats (1040B, 16B-aligned rows)
#define NSLOT 35          // H[a-2 .. a+32]

typedef float f4u __attribute__((vector_size(16), aligned(4)));

__device__ __forceinline__ float sbc(float v) {   // wave-uniform -> SGPR
    return __uint_as_float(__builtin_amdgcn_readfirstlane(__float_as_uint(v)));
}

__global__ __launch_bounds__(512) void blur_fir_kernel(
    const float* __restrict__ x,
    const float* __restrict__ k2d,
    float* __restrict__ out,
    int ntasks, int nstride)
{
    __shared__ float Hs[NSLOT * HSTR];             // 36.4 KB

    const int lane = threadIdx.x & 63;
    const int wv   = threadIdx.x >> 6;             // 0..7

    const float w0 = sbc(k2d[0]);
    const float w1 = sbc(k2d[1]);
    const float w2 = sbc(k2d[2]);
    const float w3 = sbc(k2d[3]);
    const float inv = 1.0f / w0;
    const float v1 = sbc(k2d[4]  * inv);
    const float v2 = sbc(k2d[8]  * inv);
    const float v3 = sbc(k2d[12] * inv);

    const int   c0 = lane << 2;                    // 4 cols per lane
    const float mL = (lane > 0)  ? 1.0f : 0.0f;
    const float mR = (lane < 63) ? 1.0f : 0.0f;
    const int   lm = (lane > 0)  ? lane - 1 : 0;
    const int   lp = (lane < 63) ? lane + 1 : 63;
    const bool last = (lane == 63);

    // Store one output row (257 dwords at dword offset rdw) from per-lane
    // res R (cols [4*lane, 4*lane+4)) + col-256 scalar s256 (lane 63 only),
    // using only 16B-aligned dwordx4 bulk stores.
    auto store_row = [&](size_t rdw, float4 R, float s256) {
        const int s = (int)(rdw & 3);              // wave-uniform
        if (s == 0) {
            *(float4*)(out + rdw + c0) = R;        // 16B aligned
            if (last) out[rdw + 256] = s256;
        } else {
            float Nx = __shfl(R.x, lp, 64);        // next lane's low elems
            float Ny = __shfl(R.y, lp, 64);
            float Nz = __shfl(R.z, lp, 64);
            float4 V;
            if (s == 1)      V = make_float4(R.w, Nx, Ny, Nz);
            else if (s == 2) V = make_float4(R.z, R.w, Nx, Ny);
            else             V = make_float4(R.y, R.z, R.w, Nx);
            if (lane < 63)
                *(float4*)(out + rdw + (4 - s) + c0) = V;   // 16B aligned
            if (lane == 0) {                       // head: cols 0..3-s
                out[rdw] = R.x;
                if (s <= 2) out[rdw + 1] = R.y;
                if (s == 1) out[rdw + 2] = R.z;
            }
            if (last) {                            // tail: cols 256-s..256
                out[rdw + 256] = s256;
                out[rdw + 255] = R.w;
                if (s >= 2) out[rdw + 254] = R.z;
                if (s == 3) out[rdw + 253] = R.y;
            }
        }
    };

    for (int t = blockIdx.x; t < ntasks; t += nstride) {
        const int plane = t >> 3;                  // 8 groups per plane
        const int rg    = t & 7;
        const int a     = rg << 5;                 // first output row of group
        const float* xp = x + ((size_t)plane << 16);
        const size_t pbase = (size_t)plane * (OW * OH);

        __syncthreads();                           // prev iteration done reading Hs

        // Phase 1: H slots j = wv, wv+8, ... (<35); slot j = H[a-2+j].
        #pragma unroll
        for (int j = wv; j < NSLOT; j += 8) {
            const int r = a - 2 + j;
            int rr = min(max(r, 0), IH - 1);       // clamp; mask below
            float4 Bv = *(const float4*)(xp + (rr << 8) + c0);
            float rm = (r >= 0 && r < IH) ? 1.0f : 0.0f;
            float lx = __shfl(Bv.z, lm, 64) * mL;  // x[r][c0-2]
            float ly = __shfl(Bv.w, lm, 64) * mL;  // x[r][c0-1]
            float rv = __shfl(Bv.x, lp, 64) * mR;  // x[r][c0+4]
            float4 h;
            h.x = w0 * Bv.y + w1 * Bv.x + w2 * ly   + w3 * lx;
            h.y = w0 * Bv.z + w1 * Bv.y + w2 * Bv.x + w3 * ly;
            h.z = w0 * Bv.w + w1 * Bv.z + w2 * Bv.y + w3 * Bv.x;
            h.w = w0 * rv   + w1 * Bv.w + w2 * Bv.z + w3 * Bv.y;
            float h4 = (w2 * Bv.w + w3 * Bv.z) * rm;   // col 256 (lane 63)
            h.x *= rm; h.y *= rm; h.z *= rm; h.w *= rm;
            float* hp = Hs + j * HSTR;
            *(float4*)(hp + c0) = h;               // 16B-aligned, conflict-free
            if (last) hp[256] = h4;
        }
        __syncthreads();

        // Phase 2: wave wv -> output rows a+4wv .. a+4wv+3 from slots 4wv..4wv+6.
        const int j0 = wv << 2;
        const float* hb = Hs + j0 * HSTR + c0;
        float4 h0 = *(const float4*)(hb           );
        float4 h1 = *(const float4*)(hb +     HSTR);
        float4 h2 = *(const float4*)(hb + 2 * HSTR);
        float4 h3 = *(const float4*)(hb + 3 * HSTR);
        float4 h4 = *(const float4*)(hb + 4 * HSTR);
        float4 h5 = *(const float4*)(hb + 5 * HSTR);
        float4 h6 = *(const float4*)(hb + 6 * HSTR);

        auto vcomb = [&](float4 A, float4 B, float4 C, float4 D) -> float4 {
            float4 r;
            r.x = A.x + v1 * B.x + v2 * C.x + v3 * D.x;
            r.y = A.y + v1 * B.y + v2 * C.y + v3 * D.y;
            r.z = A.z + v1 * B.z + v2 * C.z + v3 * D.z;
            r.w = A.w + v1 * B.w + v2 * C.w + v3 * D.w;
            return r;
        };

        float4 R0 = vcomb(h3, h2, h1, h0);         // row a+4wv
        float4 R1 = vcomb(h4, h3, h2, h1);
        float4 R2 = vcomb(h5, h4, h3, h2);
        float4 R3 = vcomb(h6, h5, h4, h3);

        float so0 = 0.f, so1 = 0.f, so2 = 0.f, so3 = 0.f;
        if (last) {
            const float* sp = Hs + j0 * HSTR + 256;
            float s0 = sp[0],        s1 = sp[HSTR],     s2 = sp[2 * HSTR];
            float s3 = sp[3 * HSTR], s4 = sp[4 * HSTR], s5 = sp[5 * HSTR];
            float s6 = sp[6 * HSTR];
            so0 = s3 + v1 * s2 + v2 * s1 + v3 * s0;
            so1 = s4 + v1 * s3 + v2 * s2 + v3 * s1;
            so2 = s5 + v1 * s4 + v2 * s3 + v3 * s2;
            so3 = s6 + v1 * s5 + v2 * s4 + v3 * s3;
        }

        const size_t q0 = (size_t)(a + (wv << 2));
        store_row(pbase + (q0    ) * OW, R0, so0);
        store_row(pbase + (q0 + 1) * OW, R1, so1);
        store_row(pbase + (q0 + 2) * OW, R2, so2);
        store_row(pbase + (q0 + 3) * OW, R3, so3);

        // Output row 256 (only group 7, wave 7): H[256]=H[257]=0.
        if (rg == 7 && wv == 7) {
            float4 Hm2 = *(const float4*)(Hs + 32 * HSTR + c0);  // H[254]
            float4 Hm1 = *(const float4*)(Hs + 33 * HSTR + c0);  // H[255]
            float4 R;
            R.x = v2 * Hm1.x + v3 * Hm2.x;
            R.y = v2 * Hm1.y + v3 * Hm2.y;
            R.z = v2 * Hm1.z + v3 * Hm2.z;
            R.w = v2 * Hm1.w + v3 * Hm2.w;
            float s256 = v2 * Hs[33 * HSTR + 256] + v3 * Hs[32 * HSTR + 256];
            store_row(pbase + (size_t)256 * OW, R, s256);
        }
    }
}

extern "C" void kernel_launch(void* const* d_in, const int* in_sizes, int n_in,
                              void* d_out, int out_size, void* d_ws, size_t ws_size,
                              hipStream_t stream) {
    const float* x   = (const float*)d_in[0];
    const float* k2d = (const float*)d_in[1];
    float* out = (float*)d_out;

    int nplanes = in_sizes[0] >> 16;               // B*C = 2048
    int ntasks  = nplanes * 8;                     // 16384 32-row group tasks
    int nblocks = 1024;                            // 8192 waves, 16 tasks/block

    blur_fir_kernel<<<nblocks, 512, 0, stream>>>(x, k2d, out, ntasks, nblocks);
}

// Round 17
// 210.254 us; speedup vs baseline: 1.1364x; 1.1364x over previous
//
#include <hip/hip_runtime.h>

// Depthwise separable 4x4 FIR blur (StyleGAN2 upfirdn2d, up=down=1, pad=(2,2)).
// x: [B,C,256,256] f32, kernel: [4,4] f32 separable, out: [B,C,257,257] f32.
//
// out[q] = H[q+1] + v1*H[q] + v2*H[q-1] + v3*H[q-2],  H[r][c] = sum_j w[j]*x[r][c+1-j]
//
// FINAL = R12 (best of 16 rounds, 210.6us): global-sweep task order +
// block-cooperative LDS H-staging, 32-row groups, 512-thread blocks.
//  - task = (plane, 32-output-row group); 1024 blocks stride 16384 tasks ->
//    instantaneous read window = contiguous ~33MB chunk (sweep locality).
//  - phase 1: 8 waves cooperatively compute the 35 H-rows (each input row
//    loaded ONCE as one float4/lane, halo via shfl) into LDS.
//  - phase 2: each wave builds 4 output rows from 7 LDS H-rows. Read
//    amplification 35/32 = 1.094x.
//  - LDS 35x260x4 = 36.4 KB -> 4 blocks/CU = full 32 waves/CU.
// Ladder: R1 441 -> R2 262 -> R5 247 -> R8 235 -> R11 217.6 -> R12 210.6us.
// Exhausted/refuted: NT stores (x3 regressions), global_load_lds path,
// XCD chunking, deeper amp reduction (R15 null), 64-row groups @2blk/CU
// (R13), cross-task pipelining (R14), aligned store re-slicing (R16).

#define IW 256
#define IH 256
#define OW 257
#define OH 257
#define HSTR 260          // LDS H-row stride in floats (1040B, 16B-aligned rows)
#define NSLOT 35          // H[a-2 .. a+32]

typedef float f4u __attribute__((vector_size(16), aligned(4)));

__device__ __forceinline__ float sbc(float v) {   // wave-uniform -> SGPR
    return __uint_as_float(__builtin_amdgcn_readfirstlane(__float_as_uint(v)));
}

__global__ __launch_bounds__(512) void blur_fir_kernel(
    const float* __restrict__ x,
    const float* __restrict__ k2d,
    float* __restrict__ out,
    int ntasks, int nstride)
{
    __shared__ float Hs[NSLOT * HSTR];             // 36.4 KB

    const int lane = threadIdx.x & 63;
    const int wv   = threadIdx.x >> 6;             // 0..7

    const float w0 = sbc(k2d[0]);
    const float w1 = sbc(k2d[1]);
    const float w2 = sbc(k2d[2]);
    const float w3 = sbc(k2d[3]);
    const float inv = 1.0f / w0;
    const float v1 = sbc(k2d[4]  * inv);
    const float v2 = sbc(k2d[8]  * inv);
    const float v3 = sbc(k2d[12] * inv);

    const int   c0 = lane << 2;                    // 4 cols per lane
    const float mL = (lane > 0)  ? 1.0f : 0.0f;
    const float mR = (lane < 63) ? 1.0f : 0.0f;
    const int   lm = (lane > 0)  ? lane - 1 : 0;
    const int   lp = (lane < 63) ? lane + 1 : 63;
    const bool last = (lane == 63);

    for (int t = blockIdx.x; t < ntasks; t += nstride) {
        const int plane = t >> 3;                  // 8 groups per plane
        const int rg    = t & 7;
        const int a     = rg << 5;                 // first output row of group
        const float* xp = x + ((size_t)plane << 16);

        __syncthreads();                           // prev iteration done reading Hs

        // Phase 1: H slots j = wv, wv+8, ... (<35); slot j = H[a-2+j].
        // Each input row loaded ONCE (one float4/lane), halo via shfl.
        #pragma unroll
        for (int j = wv; j < NSLOT; j += 8) {
            const int r = a - 2 + j;
            int rr = min(max(r, 0), IH - 1);       // clamp; mask below
            float4 Bv = *(const float4*)(xp + (rr << 8) + c0);
            float rm = (r >= 0 && r < IH) ? 1.0f : 0.0f;
            float lx = __shfl(Bv.z, lm, 64) * mL;  // x[r][c0-2]
            float ly = __shfl(Bv.w, lm, 64) * mL;  // x[r][c0-1]
            float rv = __shfl(Bv.x, lp, 64) * mR;  // x[r][c0+4]
            float4 h;
            h.x = w0 * Bv.y + w1 * Bv.x + w2 * ly   + w3 * lx;
            h.y = w0 * Bv.z + w1 * Bv.y + w2 * Bv.x + w3 * ly;
            h.z = w0 * Bv.w + w1 * Bv.z + w2 * Bv.y + w3 * Bv.x;
            h.w = w0 * rv   + w1 * Bv.w + w2 * Bv.z + w3 * Bv.y;
            float h4 = (w2 * Bv.w + w3 * Bv.z) * rm;   // col 256 (lane 63)
            h.x *= rm; h.y *= rm; h.z *= rm; h.w *= rm;
            float* hp = Hs + j * HSTR;
            *(float4*)(hp + c0) = h;               // 16B-aligned, conflict-free
            if (last) hp[256] = h4;
        }
        __syncthreads();

        // Phase 2: wave wv -> output rows a+4wv .. a+4wv+3 from slots 4wv..4wv+6.
        const int j0 = wv << 2;
        const float* hb = Hs + j0 * HSTR + c0;
        float4 h0 = *(const float4*)(hb           );
        float4 h1 = *(const float4*)(hb +     HSTR);
        float4 h2 = *(const float4*)(hb + 2 * HSTR);
        float4 h3 = *(const float4*)(hb + 3 * HSTR);
        float4 h4 = *(const float4*)(hb + 4 * HSTR);
        float4 h5 = *(const float4*)(hb + 5 * HSTR);
        float4 h6 = *(const float4*)(hb + 6 * HSTR);

        auto vcomb = [&](float4 A, float4 B, float4 C, float4 D) -> float4 {
            float4 r;
            r.x = A.x + v1 * B.x + v2 * C.x + v3 * D.x;
            r.y = A.y + v1 * B.y + v2 * C.y + v3 * D.y;
            r.z = A.z + v1 * B.z + v2 * C.z + v3 * D.z;
            r.w = A.w + v1 * B.w + v2 * C.w + v3 * D.w;
            return r;
        };

        float* op = out + (size_t)plane * (OW * OH)
                        + (size_t)(a + (wv << 2)) * OW + c0;
        float4 R0 = vcomb(h3, h2, h1, h0);         // row a+4wv
        float4 R1 = vcomb(h4, h3, h2, h1);
        float4 R2 = vcomb(h5, h4, h3, h2);
        float4 R3 = vcomb(h6, h5, h4, h3);
        *(f4u*)(op         ) = (f4u){R0.x, R0.y, R0.z, R0.w};
        *(f4u*)(op +     OW) = (f4u){R1.x, R1.y, R1.z, R1.w};
        *(f4u*)(op + 2 * OW) = (f4u){R2.x, R2.y, R2.z, R2.w};
        *(f4u*)(op + 3 * OW) = (f4u){R3.x, R3.y, R3.z, R3.w};
        if (last) {
            const float* sp = Hs + j0 * HSTR + 256;
            float s0 = sp[0],        s1 = sp[HSTR],     s2 = sp[2 * HSTR];
            float s3 = sp[3 * HSTR], s4 = sp[4 * HSTR], s5 = sp[5 * HSTR];
            float s6 = sp[6 * HSTR];
            op[4]          = s3 + v1 * s2 + v2 * s1 + v3 * s0;
            op[OW + 4]     = s4 + v1 * s3 + v2 * s2 + v3 * s1;
            op[2 * OW + 4] = s5 + v1 * s4 + v2 * s3 + v3 * s2;
            op[3 * OW + 4] = s6 + v1 * s5 + v2 * s4 + v3 * s3;
        }

        // Output row 256 (only group 7, wave 7): H[256]=H[257]=0.
        if (rg == 7 && wv == 7) {
            float4 Hm2 = *(const float4*)(Hs + 32 * HSTR + c0);  // H[254]
            float4 Hm1 = *(const float4*)(Hs + 33 * HSTR + c0);  // H[255]
            float4 R;
            R.x = v2 * Hm1.x + v3 * Hm2.x;
            R.y = v2 * Hm1.y + v3 * Hm2.y;
            R.z = v2 * Hm1.z + v3 * Hm2.z;
            R.w = v2 * Hm1.w + v3 * Hm2.w;
            *(f4u*)(op + 4 * OW) = (f4u){R.x, R.y, R.z, R.w};
            if (last)
                op[4 * OW + 4] = v2 * Hs[33 * HSTR + 256] + v3 * Hs[32 * HSTR + 256];
        }
    }
}

extern "C" void kernel_launch(void* const* d_in, const int* in_sizes, int n_in,
                              void* d_out, int out_size, void* d_ws, size_t ws_size,
                              hipStream_t stream) {
    const float* x   = (const float*)d_in[0];
    const float* k2d = (const float*)d_in[1];
    float* out = (float*)d_out;

    int nplanes = in_sizes[0] >> 16;               // B*C = 2048
    int ntasks  = nplanes * 8;                     // 16384 32-row group tasks
    int nblocks = 1024;                            // 8192 waves, 16 tasks/block

    blur_fir_kernel<<<nblocks, 512, 0, stream>>>(x, k2d, out, ntasks, nblocks);
}